// Round 6
// baseline (686.120 us; speedup 1.0000x reference)
//
#include <hip/hip_runtime.h>

typedef unsigned short u16;
typedef __attribute__((ext_vector_type(8))) __bf16 bf16x8;
typedef __attribute__((ext_vector_type(4))) float floatx4;

// ---------- bf16 helpers ----------
__device__ inline float bf2f(u16 u) {
    union { unsigned int i; float f; } x; x.i = ((unsigned int)u) << 16; return x.f;
}
__device__ inline u16 f2bf(float f) {
    __bf16 h = (__bf16)f; return __builtin_bit_cast(unsigned short, h);
}
__device__ inline float load_f(u16 v) { return bf2f(v); }
__device__ inline float load_f(float v) { return v; }

__device__ inline floatx4 mfma_bf16(bf16x8 a, bf16x8 b, floatx4 c) {
    return __builtin_amdgcn_mfma_f32_16x16x32_bf16(a, b, c, 0, 0, 0);
}

__device__ inline float gelu_tanh(float x) {
    float u = 0.7978845608028654f * (x + 0.044715f * x * x * x);
    u = fminf(fmaxf(u, -15.f), 15.f);
    float e = __expf(2.f * u);
    float th = (e - 1.f) / (e + 1.f);
    return 0.5f * x * (1.f + th);
}

// async global->LDS, 16B per lane; lds dest = wave-uniform base + lane*16
__device__ inline void async16(const void* g, void* l) {
    __builtin_amdgcn_global_load_lds(
        (const __attribute__((address_space(1))) unsigned int*)g,
        (__attribute__((address_space(3))) unsigned int*)l, 16, 0, 0);
}

// ---------- dtype detection: 0 = bf16 stream, 1 = f32 stream ----------
__global__ __launch_bounds__(256)
void detect_dtype(const u16* __restrict__ p, int* __restrict__ flag) {
    int t = threadIdx.x, cnt = 0;
    #pragma unroll
    for (int j = 0; j < 8; ++j) {
        unsigned e = (p[t * 8 + j] >> 7) & 0xFF;
        cnt += (e >= 100 && e <= 140) ? 1 : 0;
    }
    __shared__ int s[256];
    s[t] = cnt; __syncthreads();
    for (int off = 128; off; off >>= 1) { if (t < off) s[t] += s[t + off]; __syncthreads(); }
    if (t == 0) *flag = (s[0] < 1844) ? 1 : 0;
}

// ---------- canonicalize tgt (+fp32 X) and memory in one launch ----------
__global__ __launch_bounds__(256)
void convert_big(const void* __restrict__ tgt, const void* __restrict__ mem,
                 u16* __restrict__ tgt_c, u16* __restrict__ mem_c,
                 float* __restrict__ X, const int* __restrict__ flag) {
    int f = *flag;
    int b = blockIdx.x;
    bool isT = b < 4096;
    const void* s = isT ? tgt : mem;
    u16* d = isT ? tgt_c : mem_c;
    int i = (((isT ? b : b - 4096) * 256) + threadIdx.x) * 4;
    #pragma unroll
    for (int j = 0; j < 4; ++j) {
        float v; u16 hv;
        if (f) { v = ((const float*)s)[i + j]; hv = f2bf(v); }
        else   { hv = ((const u16*)s)[i + j]; v = bf2f(hv); }
        d[i + j] = hv;
        if (isT) X[i + j] = v;
    }
}

struct VecTab { const void* src[16]; int n[16]; int off[16]; };
__global__ __launch_bounds__(256)
void convert_vecs(VecTab tab, u16* __restrict__ dst, const int* __restrict__ flag) {
    int f = *flag;
    int b = blockIdx.x;
    const void* s = tab.src[b];
    int n = tab.n[b];
    u16* d = dst + tab.off[b];
    for (int i = threadIdx.x; i < n; i += 256)
        d[i] = f ? f2bf(((const float*)s)[i]) : ((const u16*)s)[i];
}

__global__ __launch_bounds__(256)
void store_out(const float* __restrict__ X, void* __restrict__ out, int n,
               const int* __restrict__ flag) {
    int f = *flag;
    int i = (blockIdx.x * 256 + threadIdx.x) * 4;
    if (i < n) {
        #pragma unroll
        for (int j = 0; j < 4; ++j) {
            float v = X[i + j];
            if (f) ((float*)out)[i + j] = v;
            else   ((u16*)out)[i + j] = f2bf(v);
        }
    }
}

// ---------- batched transpose: 10 segments, src[R,C] -> dst[C,R] ----------
struct TransTab {
    const void* src[10]; u16* dst[10];
    int C[10]; int start[10];
};
__global__ __launch_bounds__(256)
void transpose_batch(TransTab tb, const int* __restrict__ flag) {
    int f = *flag;
    int bid = blockIdx.x;
    int seg = 0;
    #pragma unroll
    for (int i = 1; i < 10; ++i) if (bid >= tb.start[i]) seg = i;
    int local = bid - tb.start[seg];
    const void* src = tb.src[seg];
    u16* dst = tb.dst[seg];
    int C = tb.C[seg];
    int ct = C >> 5;
    int by = local / ct, bx = local - by * ct;
    int R = (seg < 8) ? 1024 : ((seg == 8) ? 1024 : 4096);
    __shared__ u16 tile[32][33];
    int tx = threadIdx.x & 31, ty = threadIdx.x >> 5;
    int r0 = by * 32, c0 = bx * 32;
    #pragma unroll
    for (int i = 0; i < 32; i += 8) {
        size_t idx = (size_t)(r0 + ty + i) * C + c0 + tx;
        tile[ty + i][tx] = f ? f2bf(((const float*)src)[idx]) : ((const u16*)src)[idx];
    }
    __syncthreads();
    #pragma unroll
    for (int i = 0; i < 32; i += 8)
        dst[(size_t)(c0 + ty + i) * R + r0 + tx] = tile[tx][ty + i];
}

// ---------- layernorm (row = 1024) ----------
template <typename TIN>
__global__ __launch_bounds__(256)
void lnorm(const TIN* __restrict__ Xin, const u16* __restrict__ gg,
           const u16* __restrict__ bb, u16* __restrict__ Y) {
    const int row = blockIdx.x, t = threadIdx.x;
    const TIN* xr = Xin + (size_t)row * 1024;
    float x[4]; float s1 = 0.f, s2 = 0.f;
    #pragma unroll
    for (int i = 0; i < 4; ++i) {
        float v = load_f(xr[i * 256 + t]);
        x[i] = v; s1 += v; s2 += v * v;
    }
    #pragma unroll
    for (int m = 1; m < 64; m <<= 1) { s1 += __shfl_xor(s1, m, 64); s2 += __shfl_xor(s2, m, 64); }
    __shared__ float red[8];
    if ((t & 63) == 0) { red[(t >> 6) * 2] = s1; red[(t >> 6) * 2 + 1] = s2; }
    __syncthreads();
    s1 = red[0] + red[2] + red[4] + red[6];
    s2 = red[1] + red[3] + red[5] + red[7];
    float mu = s1 * (1.f / 1024.f);
    float var = s2 * (1.f / 1024.f) - mu * mu;
    float rs = rsqrtf(var + 1e-5f);
    #pragma unroll
    for (int i = 0; i < 4; ++i) {
        int idx = i * 256 + t;
        float yv = (x[i] - mu) * rs * bf2f(gg[idx]) + bf2f(bb[idx]);
        Y[(size_t)row * 1024 + idx] = f2bf(yv);
    }
}

// ---------- GEMM (BK=64, XOR-swizzled LDS): C[M,N](ldc) = A @ Bt^T + bias ----------
// epi: 0 = bf16 store, 1 = gelu->bf16, 2 = Xres[idx] += v, 3 = atomicAdd (split-K)
// Staging: lane fetches global chunk ((lane&7)^(lane>>3)) so LDS chunk c of row r
// holds global chunk c^(r&7); reader XORs the same key -> conflict-free b128 reads.
template <int TM>
__global__ __launch_bounds__(256, 4)
void gemm_bt3(const u16* __restrict__ A, const u16* __restrict__ Bt,
              const u16* __restrict__ bias, u16* __restrict__ C,
              float* __restrict__ Xres, int M, int N, int K, int ldc, int epi) {
    __shared__ alignas(16) u16 As[TM * 64];
    __shared__ alignas(16) u16 Bs[128 * 64];
    constexpr int MI = TM / 32;
    const int t = threadIdx.x;
    const int lane = t & 63, w = t >> 6;
    const int l15 = lane & 15, quad = lane >> 4;
    const int m0 = blockIdx.y * TM, n0 = blockIdx.x * 128;
    const int wm = (w >> 1) * (TM / 2), wn = (w & 1) * 64;
    const int ksl = K / gridDim.z;
    const int kb = blockIdx.z * ksl, ke = kb + ksl;
    const int srow = lane >> 3;                  // 0..7
    const int scol = ((lane & 7) ^ srow) * 8;    // swizzled source chunk
    const u16* ga = A + (size_t)(m0 + w * (TM / 4) + srow) * K + scol;
    const u16* gb = Bt + (size_t)(n0 + w * 32 + srow) * K + scol;
    u16* lA = &As[w * (TM / 4) * 64];
    u16* lB = &Bs[w * 32 * 64];
    floatx4 acc[MI][4] = {};
    const int rsw = l15 & 7;

    for (int k0 = kb; k0 < ke; k0 += 64) {
        __syncthreads();
        #pragma unroll
        for (int c = 0; c < TM / 32; ++c)
            async16(ga + (size_t)(c * 8) * K + k0, lA + c * 8 * 64);
        #pragma unroll
        for (int c = 0; c < 4; ++c)
            async16(gb + (size_t)(c * 8) * K + k0, lB + c * 8 * 64);
        __syncthreads();
        #pragma unroll
        for (int kh = 0; kh < 2; ++kh) {
            const int cofs = ((kh * 4 + quad) ^ rsw) * 8;
            bf16x8 af[MI], bfr[4];
            #pragma unroll
            for (int i = 0; i < MI; ++i)
                af[i] = *(const bf16x8*)&As[(wm + i * 16 + l15) * 64 + cofs];
            #pragma unroll
            for (int i = 0; i < 4; ++i)
                bfr[i] = *(const bf16x8*)&Bs[(wn + i * 16 + l15) * 64 + cofs];
            #pragma unroll
            for (int mi = 0; mi < MI; ++mi)
                #pragma unroll
                for (int ni = 0; ni < 4; ++ni)
                    acc[mi][ni] = mfma_bf16(af[mi], bfr[ni], acc[mi][ni]);
        }
    }

    const bool addb = (blockIdx.z == 0);
    #pragma unroll
    for (int mi = 0; mi < MI; ++mi) {
        #pragma unroll
        for (int ni = 0; ni < 4; ++ni) {
            int gn = n0 + wn + ni * 16 + l15;
            float bv = addb ? bf2f(bias[gn]) : 0.f;
            #pragma unroll
            for (int r = 0; r < 4; ++r) {
                int gm = m0 + wm + mi * 16 + quad * 4 + r;
                float v = acc[mi][ni][r] + bv;
                size_t idx = (size_t)gm * ldc + gn;
                if (epi == 0)      C[idx] = f2bf(v);
                else if (epi == 1) C[idx] = f2bf(gelu_tanh(v));
                else if (epi == 2) Xres[idx] += v;
                else               atomicAdd(&Xres[idx], v);
            }
        }
    }
}

// ---------- flash attention (q-tile = 128, exp2-domain softmax) ----------
// QKV: [B*1024, 3072] bf16 (Q 0.., K 1024.., V 2048..), head h at +h*64.
// Block: (qtile128, h, b); wave w owns q-rows [w*32, w*32+32) as 2 groups of 16.
#define SCL2 0.18033688011112042f  /* 0.125 * log2(e) */
__global__ __launch_bounds__(256, 4)
void attn_fwd3(const u16* __restrict__ QKV, u16* __restrict__ CTX, int causal) {
    __shared__ alignas(16) u16 Ks[64 * 72];   // [key][d]
    __shared__ alignas(16) u16 Vst[64 * 72];  // [d][key^swz]
    __shared__ alignas(16) u16 Sw[4][32 * 72];
    const int t = threadIdx.x;
    const int lane = t & 63, w = t >> 6;
    const int l15 = lane & 15, quad = lane >> 4;
    const int q0 = blockIdx.x * 128, h = blockIdx.y, b = blockIdx.z;
    bf16x8 aq[2][2];
    #pragma unroll
    for (int g = 0; g < 2; ++g) {
        const u16* qp = QKV + (size_t)(b * 1024 + q0 + w * 32 + g * 16 + l15) * 3072 + h * 64;
        aq[g][0] = *(const bf16x8*)(qp + quad * 8);
        aq[g][1] = *(const bf16x8*)(qp + 32 + quad * 8);
    }
    floatx4 O[2][4] = {};
    float mo[2][4], lo[2][4];
    #pragma unroll
    for (int g = 0; g < 2; ++g)
        #pragma unroll
        for (int r = 0; r < 4; ++r) { mo[g][r] = -1e30f; lo[g][r] = 0.f; }

    const int skey = t >> 2, sd0 = (t & 3) * 16;
    const int swz = skey ^ ((t & 3) << 3);
    const int kend = causal ? (q0 + 128) : 1024;
    for (int kt = 0; kt < kend; kt += 64) {
        __syncthreads();
        {
            const u16* kvb = QKV + (size_t)(b * 1024 + kt + skey) * 3072 + h * 64 + sd0;
            bf16x8 k0v = *(const bf16x8*)(kvb + 1024);
            bf16x8 k1v = *(const bf16x8*)(kvb + 1024 + 8);
            *(bf16x8*)&Ks[skey * 72 + sd0] = k0v;
            *(bf16x8*)&Ks[skey * 72 + sd0 + 8] = k1v;
            bf16x8 v0v = *(const bf16x8*)(kvb + 2048);
            bf16x8 v1v = *(const bf16x8*)(kvb + 2048 + 8);
            #pragma unroll
            for (int j = 0; j < 8; ++j) Vst[(sd0 + j) * 72 + swz] = ((u16*)&v0v)[j];
            #pragma unroll
            for (int j = 0; j < 8; ++j) Vst[(sd0 + 8 + j) * 72 + swz] = ((u16*)&v1v)[j];
        }
        __syncthreads();
        const bool domask = causal && (kt + 64 > q0);
        float al[2][4];
        #pragma unroll
        for (int g = 0; g < 2; ++g) {
            floatx4 S[4];
            #pragma unroll
            for (int kg = 0; kg < 4; ++kg) {
                bf16x8 bk0 = *(const bf16x8*)&Ks[(kg * 16 + l15) * 72 + quad * 8];
                bf16x8 bk1 = *(const bf16x8*)&Ks[(kg * 16 + l15) * 72 + 32 + quad * 8];
                floatx4 z = {};
                z = mfma_bf16(aq[g][0], bk0, z);
                z = mfma_bf16(aq[g][1], bk1, z);
                S[kg] = z;
            }
            #pragma unroll
            for (int r = 0; r < 4; ++r) {
                #pragma unroll
                for (int kg = 0; kg < 4; ++kg) {
                    float s = S[kg][r] * SCL2;
                    if (domask) {
                        int kg_glob = kt + kg * 16 + l15;
                        int qg = q0 + w * 32 + g * 16 + quad * 4 + r;
                        if (kg_glob > qg) s = -1e30f;
                    }
                    S[kg][r] = s;
                }
                float v = fmaxf(fmaxf(S[0][r], S[1][r]), fmaxf(S[2][r], S[3][r]));
                #pragma unroll
                for (int msk = 1; msk < 16; msk <<= 1) v = fmaxf(v, __shfl_xor(v, msk, 64));
                float mn = fmaxf(mo[g][r], v);
                al[g][r] = exp2f(mo[g][r] - mn);
                float ssum = 0.f;
                #pragma unroll
                for (int kg = 0; kg < 4; ++kg) {
                    float p = exp2f(S[kg][r] - mn);
                    S[kg][r] = p; ssum += p;
                }
                #pragma unroll
                for (int msk = 1; msk < 16; msk <<= 1) ssum += __shfl_xor(ssum, msk, 64);
                lo[g][r] = lo[g][r] * al[g][r] + ssum;
                mo[g][r] = mn;
            }
            #pragma unroll
            for (int kg = 0; kg < 4; ++kg)
                #pragma unroll
                for (int r = 0; r < 4; ++r)
                    Sw[w][(g * 16 + quad * 4 + r) * 72 + kg * 16 + l15] = f2bf(S[kg][r]);
        }
        #pragma unroll
        for (int g = 0; g < 2; ++g)
            #pragma unroll
            for (int vg = 0; vg < 4; ++vg)
                #pragma unroll
                for (int r = 0; r < 4; ++r)
                    O[g][vg][r] *= al[g][r];
        bf16x8 ap[2][2];
        #pragma unroll
        for (int g = 0; g < 2; ++g) {
            ap[g][0] = *(const bf16x8*)&Sw[w][(g * 16 + l15) * 72 + quad * 8];
            ap[g][1] = *(const bf16x8*)&Sw[w][(g * 16 + l15) * 72 + 32 + quad * 8];
        }
        #pragma unroll
        for (int vg = 0; vg < 4; ++vg) {
            bf16x8 bv0 = *(const bf16x8*)&Vst[(vg * 16 + l15) * 72 + ((quad ^ vg) << 3)];
            bf16x8 bv1 = *(const bf16x8*)&Vst[(vg * 16 + l15) * 72 + 32 + ((quad ^ vg) << 3)];
            #pragma unroll
            for (int g = 0; g < 2; ++g) {
                O[g][vg] = mfma_bf16(ap[g][0], bv0, O[g][vg]);
                O[g][vg] = mfma_bf16(ap[g][1], bv1, O[g][vg]);
            }
        }
    }
    #pragma unroll
    for (int g = 0; g < 2; ++g)
        #pragma unroll
        for (int r = 0; r < 4; ++r) {
            float inv = 1.0f / lo[g][r];
            int qg = q0 + w * 32 + g * 16 + quad * 4 + r;
            #pragma unroll
            for (int vg = 0; vg < 4; ++vg)
                CTX[(size_t)(b * 1024 + qg) * 1024 + h * 64 + vg * 16 + l15] =
                    f2bf(O[g][vg][r] * inv);
        }
}

// ---------- launch ----------
extern "C" void kernel_launch(void* const* d_in, const int* in_sizes, int n_in,
                              void* d_out, int out_size, void* d_ws, size_t ws_size,
                              hipStream_t stream) {
    const void* tgt_raw    = d_in[0];
    const void* memory_raw = d_in[1];

    char* ws = (char*)d_ws;
    const size_t MiB = 1024 * 1024;
    float* X   = (float*)ws;                  // 0..16 MiB fp32 residual
    u16* Y     = (u16*)(ws + 16 * MiB);       // 16..24
    u16* QKV   = (u16*)(ws + 24 * MiB);       // 24..48  [4096,3072]
    u16* CTX   = (u16*)(ws + 48 * MiB);       // 48..56
    u16* H1    = (u16*)(ws + 24 * MiB);       // 24..56 (overlaps QKV/CTX, dead by FFN)
    u16* wt    = (u16*)(ws + 56 * MiB);       // 56..88 transposed weights
    u16* wqkv_s = wt;                         // [3072,1024]
    u16* wo_s  = wt + 3 * 1048576;
    u16* wq_c  = wt + 4 * 1048576;
    u16* wkv_c = wt + 5 * 1048576;            // [2048,1024]
    u16* wo_c  = wt + 7 * 1048576;
    u16* w1t   = wt + 8 * 1048576;            // [4096,1024]
    u16* w2t   = wt + 12 * 1048576;           // [1024,4096]
    u16* tgt_c = (u16*)(ws + 88 * MiB);
    u16* mem_c = (u16*)(ws + 96 * MiB);
    u16* vecs  = (u16*)(ws + 104 * MiB);
    int* flag  = (int*)(ws + 105 * MiB);

    dim3 blk(256);
    detect_dtype<<<1, blk, 0, stream>>>((const u16*)tgt_raw, flag);
    convert_big<<<8192, blk, 0, stream>>>(tgt_raw, memory_raw, tgt_c, mem_c, X, flag);

    VecTab tab;
    const int srcIdx[16] = {5, 7, 9, 11, 13, 15, 17, 19, 20, 21, 22, 23, 24, 25, 27, 29};
    const int offs[16]   = {0, 1024, 2048, 3072, 4096, 5120, 6144, 7168,
                            8192, 9216, 10240, 11264, 12288, 13312, 14336, 18432};
    for (int i = 0; i < 16; ++i) {
        tab.src[i] = d_in[srcIdx[i]];
        tab.n[i] = (i == 14) ? 4096 : 1024;
        tab.off[i] = offs[i];
    }
    convert_vecs<<<16, blk, 0, stream>>>(tab, vecs, flag);
    u16* b_qkv_s = vecs;            u16* b_o_s  = vecs + 3072;
    u16* b_q_c   = vecs + 4096;     u16* b_kv_c = vecs + 5120;
    u16* b_o_c   = vecs + 7168;
    u16* g1 = vecs + 8192;  u16* be1 = vecs + 9216;
    u16* g2 = vecs + 10240; u16* be2 = vecs + 11264;
    u16* g3 = vecs + 12288; u16* be3 = vecs + 13312;
    u16* b_ff1 = vecs + 14336; u16* b_ff2 = vecs + 18432;

    TransTab tt;
    const void* tsrc[10] = {d_in[4], d_in[6], d_in[8], d_in[10], d_in[12],
                            d_in[14], d_in[16], d_in[18], d_in[26], d_in[28]};
    u16* tdst[10] = {wqkv_s, wqkv_s + 1048576, wqkv_s + 2 * 1048576, wo_s, wq_c,
                     wkv_c, wkv_c + 1048576, wo_c, w1t, w2t};
    int start = 0;
    for (int i = 0; i < 10; ++i) {
        tt.src[i] = tsrc[i]; tt.dst[i] = tdst[i];
        tt.C[i] = (i == 8) ? 4096 : 1024;
        tt.start[i] = start;
        int R = (i == 9) ? 4096 : 1024;
        start += (R / 32) * (tt.C[i] / 32);
    }
    transpose_batch<<<start, blk, 0, stream>>>(tt, flag);

    const int NTOK = 4096;
    dim3 gQKV(24, 32);         // TM=128
    dim3 gKV(16, 64);          // TM=64
    dim3 gFF1(32, 32);         // TM=128
    dim3 gN1k(8, 64);          // TM=64
    dim3 gFF2(8, 64, 2);       // TM=64 + split-K x2
    dim3 ga(8, 16, 4);

    // sublayer 1: self attention (fused QKV projection)
    lnorm<u16><<<4096, blk, 0, stream>>>(tgt_c, g1, be1, Y);
    gemm_bt3<128><<<gQKV, blk, 0, stream>>>(Y, wqkv_s, b_qkv_s, QKV, nullptr, NTOK, 3072, 1024, 3072, 0);
    attn_fwd3<<<ga, blk, 0, stream>>>(QKV, CTX, 1);
    gemm_bt3<64><<<gN1k, blk, 0, stream>>>(CTX, wo_s, b_o_s, nullptr, X, NTOK, 1024, 1024, 1024, 2);

    // sublayer 2: cross attention (fused KV projection from memory)
    lnorm<float><<<4096, blk, 0, stream>>>(X, g2, be2, Y);
    gemm_bt3<64><<<gN1k, blk, 0, stream>>>(Y, wq_c, b_q_c, QKV, nullptr, NTOK, 1024, 1024, 3072, 0);
    gemm_bt3<64><<<gKV, blk, 0, stream>>>(mem_c, wkv_c, b_kv_c, QKV + 1024, nullptr, NTOK, 2048, 1024, 3072, 0);
    attn_fwd3<<<ga, blk, 0, stream>>>(QKV, CTX, 0);
    gemm_bt3<64><<<gN1k, blk, 0, stream>>>(CTX, wo_c, b_o_c, nullptr, X, NTOK, 1024, 1024, 1024, 2);

    // sublayer 3: FFN
    lnorm<float><<<4096, blk, 0, stream>>>(X, g3, be3, Y);
    gemm_bt3<128><<<gFF1, blk, 0, stream>>>(Y, w1t, b_ff1, H1, nullptr, NTOK, 4096, 1024, 4096, 1);
    gemm_bt3<64><<<gFF2, blk, 0, stream>>>(H1, w2t, b_ff2, nullptr, X, NTOK, 1024, 4096, 1024, 3);

    store_out<<<4096, blk, 0, stream>>>(X, d_out, NTOK * 1024, flag);
}

// Round 7
// 642.220 us; speedup vs baseline: 1.0684x; 1.0684x over previous
//
#include <hip/hip_runtime.h>

typedef unsigned short u16;
typedef __attribute__((ext_vector_type(8))) __bf16 bf16x8;
typedef __attribute__((ext_vector_type(4))) float floatx4;

// ---------- bf16 helpers ----------
__device__ inline float bf2f(u16 u) {
    union { unsigned int i; float f; } x; x.i = ((unsigned int)u) << 16; return x.f;
}
__device__ inline u16 f2bf(float f) {
    __bf16 h = (__bf16)f; return __builtin_bit_cast(unsigned short, h);
}
__device__ inline float load_f(u16 v) { return bf2f(v); }
__device__ inline float load_f(float v) { return v; }

__device__ inline floatx4 mfma_bf16(bf16x8 a, bf16x8 b, floatx4 c) {
    return __builtin_amdgcn_mfma_f32_16x16x32_bf16(a, b, c, 0, 0, 0);
}

__device__ inline float gelu_tanh(float x) {
    float u = 0.7978845608028654f * (x + 0.044715f * x * x * x);
    u = fminf(fmaxf(u, -15.f), 15.f);
    float e = __expf(2.f * u);
    float th = (e - 1.f) / (e + 1.f);
    return 0.5f * x * (1.f + th);
}

// async global->LDS, 16B per lane; lds dest = wave-uniform base + lane*16
__device__ inline void async16(const void* g, void* l) {
    __builtin_amdgcn_global_load_lds(
        (const __attribute__((address_space(1))) unsigned int*)g,
        (__attribute__((address_space(3))) unsigned int*)l, 16, 0, 0);
}

// ---------- dtype detection: 0 = bf16 stream, 1 = f32 stream ----------
__global__ __launch_bounds__(256)
void detect_dtype(const u16* __restrict__ p, int* __restrict__ flag) {
    int t = threadIdx.x, cnt = 0;
    #pragma unroll
    for (int j = 0; j < 8; ++j) {
        unsigned e = (p[t * 8 + j] >> 7) & 0xFF;
        cnt += (e >= 100 && e <= 140) ? 1 : 0;
    }
    __shared__ int s[256];
    s[t] = cnt; __syncthreads();
    for (int off = 128; off; off >>= 1) { if (t < off) s[t] += s[t + off]; __syncthreads(); }
    if (t == 0) *flag = (s[0] < 1844) ? 1 : 0;
}

// ---------- canonicalize tgt (+fp32 X) and memory in one launch ----------
__global__ __launch_bounds__(256)
void convert_big(const void* __restrict__ tgt, const void* __restrict__ mem,
                 u16* __restrict__ tgt_c, u16* __restrict__ mem_c,
                 float* __restrict__ X, const int* __restrict__ flag) {
    int f = *flag;
    int b = blockIdx.x;
    bool isT = b < 4096;
    const void* s = isT ? tgt : mem;
    u16* d = isT ? tgt_c : mem_c;
    int i = (((isT ? b : b - 4096) * 256) + threadIdx.x) * 4;
    #pragma unroll
    for (int j = 0; j < 4; ++j) {
        float v; u16 hv;
        if (f) { v = ((const float*)s)[i + j]; hv = f2bf(v); }
        else   { hv = ((const u16*)s)[i + j]; v = bf2f(hv); }
        d[i + j] = hv;
        if (isT) X[i + j] = v;
    }
}

struct VecTab { const void* src[16]; int n[16]; int off[16]; };
__global__ __launch_bounds__(256)
void convert_vecs(VecTab tab, u16* __restrict__ dst, const int* __restrict__ flag) {
    int f = *flag;
    int b = blockIdx.x;
    const void* s = tab.src[b];
    int n = tab.n[b];
    u16* d = dst + tab.off[b];
    for (int i = threadIdx.x; i < n; i += 256)
        d[i] = f ? f2bf(((const float*)s)[i]) : ((const u16*)s)[i];
}

__global__ __launch_bounds__(256)
void store_out(const float* __restrict__ X, void* __restrict__ out, int n,
               const int* __restrict__ flag) {
    int f = *flag;
    int i = (blockIdx.x * 256 + threadIdx.x) * 4;
    if (i < n) {
        #pragma unroll
        for (int j = 0; j < 4; ++j) {
            float v = X[i + j];
            if (f) ((float*)out)[i + j] = v;
            else   ((u16*)out)[i + j] = f2bf(v);
        }
    }
}

// ---------- batched transpose: 10 segments, src[R,C] -> dst[C,R] ----------
struct TransTab {
    const void* src[10]; u16* dst[10];
    int C[10]; int start[10];
};
__global__ __launch_bounds__(256)
void transpose_batch(TransTab tb, const int* __restrict__ flag) {
    int f = *flag;
    int bid = blockIdx.x;
    int seg = 0;
    #pragma unroll
    for (int i = 1; i < 10; ++i) if (bid >= tb.start[i]) seg = i;
    int local = bid - tb.start[seg];
    const void* src = tb.src[seg];
    u16* dst = tb.dst[seg];
    int C = tb.C[seg];
    int ct = C >> 5;
    int by = local / ct, bx = local - by * ct;
    int R = (seg < 8) ? 1024 : ((seg == 8) ? 1024 : 4096);
    __shared__ u16 tile[32][33];
    int tx = threadIdx.x & 31, ty = threadIdx.x >> 5;
    int r0 = by * 32, c0 = bx * 32;
    #pragma unroll
    for (int i = 0; i < 32; i += 8) {
        size_t idx = (size_t)(r0 + ty + i) * C + c0 + tx;
        tile[ty + i][tx] = f ? f2bf(((const float*)src)[idx]) : ((const u16*)src)[idx];
    }
    __syncthreads();
    #pragma unroll
    for (int i = 0; i < 32; i += 8)
        dst[(size_t)(c0 + ty + i) * R + r0 + tx] = tile[tx][ty + i];
}

// ---------- layernorm (row = 1024) ----------
template <typename TIN>
__global__ __launch_bounds__(256)
void lnorm(const TIN* __restrict__ Xin, const u16* __restrict__ gg,
           const u16* __restrict__ bb, u16* __restrict__ Y) {
    const int row = blockIdx.x, t = threadIdx.x;
    const TIN* xr = Xin + (size_t)row * 1024;
    float x[4]; float s1 = 0.f, s2 = 0.f;
    #pragma unroll
    for (int i = 0; i < 4; ++i) {
        float v = load_f(xr[i * 256 + t]);
        x[i] = v; s1 += v; s2 += v * v;
    }
    #pragma unroll
    for (int m = 1; m < 64; m <<= 1) { s1 += __shfl_xor(s1, m, 64); s2 += __shfl_xor(s2, m, 64); }
    __shared__ float red[8];
    if ((t & 63) == 0) { red[(t >> 6) * 2] = s1; red[(t >> 6) * 2 + 1] = s2; }
    __syncthreads();
    s1 = red[0] + red[2] + red[4] + red[6];
    s2 = red[1] + red[3] + red[5] + red[7];
    float mu = s1 * (1.f / 1024.f);
    float var = s2 * (1.f / 1024.f) - mu * mu;
    float rs = rsqrtf(var + 1e-5f);
    #pragma unroll
    for (int i = 0; i < 4; ++i) {
        int idx = i * 256 + t;
        float yv = (x[i] - mu) * rs * bf2f(gg[idx]) + bf2f(bb[idx]);
        Y[(size_t)row * 1024 + idx] = f2bf(yv);
    }
}

// ---------- GEMM (BK=64, XOR-swizzled LDS): C[M,N](ldc) = A @ Bt^T + bias ----------
// epi: 0 = bf16 store, 1 = gelu->bf16, 2 = Xres[idx] += v, 3 = atomicAdd (split-K)
template <int TM>
__global__ __launch_bounds__(256, 4)
void gemm_bt3(const u16* __restrict__ A, const u16* __restrict__ Bt,
              const u16* __restrict__ bias, u16* __restrict__ C,
              float* __restrict__ Xres, int M, int N, int K, int ldc, int epi) {
    __shared__ alignas(16) u16 As[TM * 64];
    __shared__ alignas(16) u16 Bs[128 * 64];
    constexpr int MI = TM / 32;
    const int t = threadIdx.x;
    const int lane = t & 63, w = t >> 6;
    const int l15 = lane & 15, quad = lane >> 4;
    const int m0 = blockIdx.y * TM, n0 = blockIdx.x * 128;
    const int wm = (w >> 1) * (TM / 2), wn = (w & 1) * 64;
    const int ksl = K / gridDim.z;
    const int kb = blockIdx.z * ksl, ke = kb + ksl;
    const int srow = lane >> 3;                  // 0..7
    const int scol = ((lane & 7) ^ srow) * 8;    // swizzled source chunk
    const u16* ga = A + (size_t)(m0 + w * (TM / 4) + srow) * K + scol;
    const u16* gb = Bt + (size_t)(n0 + w * 32 + srow) * K + scol;
    u16* lA = &As[w * (TM / 4) * 64];
    u16* lB = &Bs[w * 32 * 64];
    floatx4 acc[MI][4] = {};
    const int rsw = l15 & 7;

    for (int k0 = kb; k0 < ke; k0 += 64) {
        __syncthreads();
        #pragma unroll
        for (int c = 0; c < TM / 32; ++c)
            async16(ga + (size_t)(c * 8) * K + k0, lA + c * 8 * 64);
        #pragma unroll
        for (int c = 0; c < 4; ++c)
            async16(gb + (size_t)(c * 8) * K + k0, lB + c * 8 * 64);
        __syncthreads();
        #pragma unroll
        for (int kh = 0; kh < 2; ++kh) {
            const int cofs = ((kh * 4 + quad) ^ rsw) * 8;
            bf16x8 af[MI], bfr[4];
            #pragma unroll
            for (int i = 0; i < MI; ++i)
                af[i] = *(const bf16x8*)&As[(wm + i * 16 + l15) * 64 + cofs];
            #pragma unroll
            for (int i = 0; i < 4; ++i)
                bfr[i] = *(const bf16x8*)&Bs[(wn + i * 16 + l15) * 64 + cofs];
            #pragma unroll
            for (int mi = 0; mi < MI; ++mi)
                #pragma unroll
                for (int ni = 0; ni < 4; ++ni)
                    acc[mi][ni] = mfma_bf16(af[mi], bfr[ni], acc[mi][ni]);
        }
    }

    const bool addb = (blockIdx.z == 0);
    #pragma unroll
    for (int mi = 0; mi < MI; ++mi) {
        #pragma unroll
        for (int ni = 0; ni < 4; ++ni) {
            int gn = n0 + wn + ni * 16 + l15;
            float bv = addb ? bf2f(bias[gn]) : 0.f;
            #pragma unroll
            for (int r = 0; r < 4; ++r) {
                int gm = m0 + wm + mi * 16 + quad * 4 + r;
                float v = acc[mi][ni][r] + bv;
                size_t idx = (size_t)gm * ldc + gn;
                if (epi == 0)      C[idx] = f2bf(v);
                else if (epi == 1) C[idx] = f2bf(gelu_tanh(v));
                else if (epi == 2) Xres[idx] += v;
                else               atomicAdd(&Xres[idx], v);
            }
        }
    }
}

// ---------- flash attention v4: q-tile 64, ones-column MFMA row-sum ----------
// QKV: [B*1024, 3072] bf16 (Q 0.., K 1024.., V 2048..), head h at +h*64.
#define SCL2 0.18033688011112042f  /* 0.125 * log2(e) */
__global__ __launch_bounds__(256, 4)
void attn_fwd4(const u16* __restrict__ QKV, u16* __restrict__ CTX, int causal) {
    __shared__ alignas(16) u16 Ks[64 * 72];   // [key][d]
    __shared__ alignas(16) u16 Vst[64 * 72];  // [d][key^swz]
    __shared__ alignas(16) u16 Sw[4][16 * 72];
    const int t = threadIdx.x;
    const int lane = t & 63, w = t >> 6;
    const int l15 = lane & 15, quad = lane >> 4;
    const int q0 = blockIdx.x * 64, h = blockIdx.y, b = blockIdx.z;
    const int qrow = q0 + w * 16 + l15;
    const u16* qp = QKV + (size_t)(b * 1024 + qrow) * 3072 + h * 64;
    bf16x8 aq0 = *(const bf16x8*)(qp + quad * 8);
    bf16x8 aq1 = *(const bf16x8*)(qp + 32 + quad * 8);
    floatx4 O[4] = {};
    floatx4 Os = {};             // row-sum accumulator (P @ ones)
    float mo[4];
    #pragma unroll
    for (int r = 0; r < 4; ++r) mo[r] = -1e30f;
    bf16x8 ones;
    #pragma unroll
    for (int j = 0; j < 8; ++j) ones[j] = (__bf16)1.0f;

    const int skey = t >> 2, snn = t & 3, sd0 = (t & 3) * 16;
    const int swz = skey ^ (snn << 3);
    const int kend = causal ? (q0 + 64) : 1024;
    for (int kt = 0; kt < kend; kt += 64) {
        __syncthreads();
        {
            const u16* kvb = QKV + (size_t)(b * 1024 + kt + skey) * 3072 + h * 64 + sd0;
            bf16x8 k0v = *(const bf16x8*)(kvb + 1024);
            bf16x8 k1v = *(const bf16x8*)(kvb + 1024 + 8);
            *(bf16x8*)&Ks[skey * 72 + sd0] = k0v;
            *(bf16x8*)&Ks[skey * 72 + sd0 + 8] = k1v;
            bf16x8 v0v = *(const bf16x8*)(kvb + 2048);
            bf16x8 v1v = *(const bf16x8*)(kvb + 2048 + 8);
            #pragma unroll
            for (int j = 0; j < 8; ++j) Vst[(sd0 + j) * 72 + swz] = ((u16*)&v0v)[j];
            #pragma unroll
            for (int j = 0; j < 8; ++j) Vst[(sd0 + 8 + j) * 72 + swz] = ((u16*)&v1v)[j];
        }
        __syncthreads();
        floatx4 S[4];
        #pragma unroll
        for (int kg = 0; kg < 4; ++kg) {
            bf16x8 bk0 = *(const bf16x8*)&Ks[(kg * 16 + l15) * 72 + quad * 8];
            bf16x8 bk1 = *(const bf16x8*)&Ks[(kg * 16 + l15) * 72 + 32 + quad * 8];
            floatx4 z = {};
            z = mfma_bf16(aq0, bk0, z);
            z = mfma_bf16(aq1, bk1, z);
            S[kg] = z;
        }
        const bool domask = causal && (kt == q0);
        float al[4];
        #pragma unroll
        for (int r = 0; r < 4; ++r) {
            #pragma unroll
            for (int kg = 0; kg < 4; ++kg) {
                float s = S[kg][r] * SCL2;   // log2-domain
                if (domask) {
                    int kg_glob = kt + kg * 16 + l15;
                    int qg = q0 + w * 16 + quad * 4 + r;
                    if (kg_glob > qg) s = -1e30f;
                }
                S[kg][r] = s;
            }
            float v = fmaxf(fmaxf(S[0][r], S[1][r]), fmaxf(S[2][r], S[3][r]));
            #pragma unroll
            for (int msk = 1; msk < 16; msk <<= 1) v = fmaxf(v, __shfl_xor(v, msk, 64));
            float mn = fmaxf(mo[r], v);
            al[r] = exp2f(mo[r] - mn);
            #pragma unroll
            for (int kg = 0; kg < 4; ++kg)
                S[kg][r] = exp2f(S[kg][r] - mn);
            mo[r] = mn;
        }
        #pragma unroll
        for (int kg = 0; kg < 4; ++kg)
            #pragma unroll
            for (int r = 0; r < 4; ++r)
                Sw[w][(quad * 4 + r) * 72 + kg * 16 + l15] = f2bf(S[kg][r]);
        #pragma unroll
        for (int g = 0; g < 4; ++g)
            #pragma unroll
            for (int r = 0; r < 4; ++r)
                O[g][r] *= al[r];
        #pragma unroll
        for (int r = 0; r < 4; ++r) Os[r] *= al[r];
        bf16x8 ap0 = *(const bf16x8*)&Sw[w][l15 * 72 + quad * 8];
        bf16x8 ap1 = *(const bf16x8*)&Sw[w][l15 * 72 + 32 + quad * 8];
        #pragma unroll
        for (int g = 0; g < 4; ++g) {
            bf16x8 bv0 = *(const bf16x8*)&Vst[(g * 16 + l15) * 72 + ((quad ^ g) << 3)];
            bf16x8 bv1 = *(const bf16x8*)&Vst[(g * 16 + l15) * 72 + 32 + ((quad ^ g) << 3)];
            O[g] = mfma_bf16(ap0, bv0, O[g]);
            O[g] = mfma_bf16(ap1, bv1, O[g]);
        }
        Os = mfma_bf16(ap0, ones, Os);
        Os = mfma_bf16(ap1, ones, Os);
    }
    #pragma unroll
    for (int r = 0; r < 4; ++r) {
        float inv = 1.0f / Os[r];
        int qg = q0 + w * 16 + quad * 4 + r;
        #pragma unroll
        for (int g = 0; g < 4; ++g)
            CTX[(size_t)(b * 1024 + qg) * 1024 + h * 64 + g * 16 + l15] = f2bf(O[g][r] * inv);
    }
}

// ---------- launch ----------
extern "C" void kernel_launch(void* const* d_in, const int* in_sizes, int n_in,
                              void* d_out, int out_size, void* d_ws, size_t ws_size,
                              hipStream_t stream) {
    const void* tgt_raw    = d_in[0];
    const void* memory_raw = d_in[1];

    char* ws = (char*)d_ws;
    const size_t MiB = 1024 * 1024;
    float* X   = (float*)ws;                  // 0..16 MiB fp32 residual
    u16* Y     = (u16*)(ws + 16 * MiB);       // 16..24
    u16* QKV   = (u16*)(ws + 24 * MiB);       // 24..48  [4096,3072]
    u16* CTX   = (u16*)(ws + 48 * MiB);       // 48..56
    u16* H1    = (u16*)(ws + 24 * MiB);       // 24..56 (overlaps QKV/CTX, dead by FFN)
    u16* wt    = (u16*)(ws + 56 * MiB);       // 56..88 transposed weights
    u16* wqkv_s = wt;                         // [3072,1024]
    u16* wo_s  = wt + 3 * 1048576;
    u16* wq_c  = wt + 4 * 1048576;
    u16* wkv_c = wt + 5 * 1048576;            // [2048,1024]
    u16* wo_c  = wt + 7 * 1048576;
    u16* w1t   = wt + 8 * 1048576;            // [4096,1024]
    u16* w2t   = wt + 12 * 1048576;           // [1024,4096]
    u16* tgt_c = (u16*)(ws + 88 * MiB);
    u16* mem_c = (u16*)(ws + 96 * MiB);
    u16* vecs  = (u16*)(ws + 104 * MiB);
    int* flag  = (int*)(ws + 105 * MiB);

    dim3 blk(256);
    detect_dtype<<<1, blk, 0, stream>>>((const u16*)tgt_raw, flag);
    convert_big<<<8192, blk, 0, stream>>>(tgt_raw, memory_raw, tgt_c, mem_c, X, flag);

    VecTab tab;
    const int srcIdx[16] = {5, 7, 9, 11, 13, 15, 17, 19, 20, 21, 22, 23, 24, 25, 27, 29};
    const int offs[16]   = {0, 1024, 2048, 3072, 4096, 5120, 6144, 7168,
                            8192, 9216, 10240, 11264, 12288, 13312, 14336, 18432};
    for (int i = 0; i < 16; ++i) {
        tab.src[i] = d_in[srcIdx[i]];
        tab.n[i] = (i == 14) ? 4096 : 1024;
        tab.off[i] = offs[i];
    }
    convert_vecs<<<16, blk, 0, stream>>>(tab, vecs, flag);
    u16* b_qkv_s = vecs;            u16* b_o_s  = vecs + 3072;
    u16* b_q_c   = vecs + 4096;     u16* b_kv_c = vecs + 5120;
    u16* b_o_c   = vecs + 7168;
    u16* g1 = vecs + 8192;  u16* be1 = vecs + 9216;
    u16* g2 = vecs + 10240; u16* be2 = vecs + 11264;
    u16* g3 = vecs + 12288; u16* be3 = vecs + 13312;
    u16* b_ff1 = vecs + 14336; u16* b_ff2 = vecs + 18432;

    TransTab tt;
    const void* tsrc[10] = {d_in[4], d_in[6], d_in[8], d_in[10], d_in[12],
                            d_in[14], d_in[16], d_in[18], d_in[26], d_in[28]};
    u16* tdst[10] = {wqkv_s, wqkv_s + 1048576, wqkv_s + 2 * 1048576, wo_s, wq_c,
                     wkv_c, wkv_c + 1048576, wo_c, w1t, w2t};
    int start = 0;
    for (int i = 0; i < 10; ++i) {
        tt.src[i] = tsrc[i]; tt.dst[i] = tdst[i];
        tt.C[i] = (i == 8) ? 4096 : 1024;
        tt.start[i] = start;
        int R = (i == 9) ? 4096 : 1024;
        start += (R / 32) * (tt.C[i] / 32);
    }
    transpose_batch<<<start, blk, 0, stream>>>(tt, flag);

    const int NTOK = 4096;
    dim3 gQKV(24, 32);         // TM=128
    dim3 gKV(16, 64);          // TM=64
    dim3 gFF1(32, 32);         // TM=128
    dim3 gN1k(8, 64);          // TM=64
    dim3 gFF2(8, 64, 2);       // TM=64 + split-K x2
    dim3 ga(16, 16, 4);

    // sublayer 1: self attention (fused QKV projection)
    lnorm<u16><<<4096, blk, 0, stream>>>(tgt_c, g1, be1, Y);
    gemm_bt3<128><<<gQKV, blk, 0, stream>>>(Y, wqkv_s, b_qkv_s, QKV, nullptr, NTOK, 3072, 1024, 3072, 0);
    attn_fwd4<<<ga, blk, 0, stream>>>(QKV, CTX, 1);
    gemm_bt3<64><<<gN1k, blk, 0, stream>>>(CTX, wo_s, b_o_s, nullptr, X, NTOK, 1024, 1024, 1024, 2);

    // sublayer 2: cross attention (fused KV projection from memory)
    lnorm<float><<<4096, blk, 0, stream>>>(X, g2, be2, Y);
    gemm_bt3<64><<<gN1k, blk, 0, stream>>>(Y, wq_c, b_q_c, QKV, nullptr, NTOK, 1024, 1024, 3072, 0);
    gemm_bt3<64><<<gKV, blk, 0, stream>>>(mem_c, wkv_c, b_kv_c, QKV + 1024, nullptr, NTOK, 2048, 1024, 3072, 0);
    attn_fwd4<<<ga, blk, 0, stream>>>(QKV, CTX, 0);
    gemm_bt3<64><<<gN1k, blk, 0, stream>>>(CTX, wo_c, b_o_c, nullptr, X, NTOK, 1024, 1024, 1024, 2);

    // sublayer 3: FFN
    lnorm<float><<<4096, blk, 0, stream>>>(X, g3, be3, Y);
    gemm_bt3<128><<<gFF1, blk, 0, stream>>>(Y, w1t, b_ff1, H1, nullptr, NTOK, 4096, 1024, 4096, 1);
    gemm_bt3<64><<<gFF2, blk, 0, stream>>>(H1, w2t, b_ff2, nullptr, X, NTOK, 1024, 4096, 1024, 3);

    store_out<<<4096, blk, 0, stream>>>(X, d_out, NTOK * 1024, flag);
}

// Round 8
// 604.631 us; speedup vs baseline: 1.1348x; 1.0622x over previous
//
#include <hip/hip_runtime.h>

typedef unsigned short u16;
typedef __attribute__((ext_vector_type(8))) __bf16 bf16x8;
typedef __attribute__((ext_vector_type(4))) float floatx4;

// ---------- bf16 helpers ----------
__device__ inline float bf2f(u16 u) {
    union { unsigned int i; float f; } x; x.i = ((unsigned int)u) << 16; return x.f;
}
__device__ inline u16 f2bf(float f) {
    __bf16 h = (__bf16)f; return __builtin_bit_cast(unsigned short, h);
}
__device__ inline float load_f(u16 v) { return bf2f(v); }
__device__ inline float load_f(float v) { return v; }

__device__ inline floatx4 mfma_bf16(bf16x8 a, bf16x8 b, floatx4 c) {
    return __builtin_amdgcn_mfma_f32_16x16x32_bf16(a, b, c, 0, 0, 0);
}

__device__ inline float gelu_tanh(float x) {
    float u = 0.7978845608028654f * (x + 0.044715f * x * x * x);
    u = fminf(fmaxf(u, -15.f), 15.f);
    float e = __expf(2.f * u);
    float th = (e - 1.f) / (e + 1.f);
    return 0.5f * x * (1.f + th);
}

// async global->LDS, 16B per lane; lds dest = wave-uniform base + lane*16
__device__ inline void async16(const void* g, void* l) {
    __builtin_amdgcn_global_load_lds(
        (const __attribute__((address_space(1))) unsigned int*)g,
        (__attribute__((address_space(3))) unsigned int*)l, 16, 0, 0);
}

// ---------- dtype detection: 0 = bf16 stream, 1 = f32 stream ----------
__global__ __launch_bounds__(256)
void detect_dtype(const u16* __restrict__ p, int* __restrict__ flag) {
    int t = threadIdx.x, cnt = 0;
    #pragma unroll
    for (int j = 0; j < 8; ++j) {
        unsigned e = (p[t * 8 + j] >> 7) & 0xFF;
        cnt += (e >= 100 && e <= 140) ? 1 : 0;
    }
    __shared__ int s[256];
    s[t] = cnt; __syncthreads();
    for (int off = 128; off; off >>= 1) { if (t < off) s[t] += s[t + off]; __syncthreads(); }
    if (t == 0) *flag = (s[0] < 1844) ? 1 : 0;
}

// ---------- canonicalize tgt (+fp32 X) and memory in one launch ----------
__global__ __launch_bounds__(256)
void convert_big(const void* __restrict__ tgt, const void* __restrict__ mem,
                 u16* __restrict__ tgt_c, u16* __restrict__ mem_c,
                 float* __restrict__ X, const int* __restrict__ flag) {
    int f = *flag;
    int b = blockIdx.x;
    bool isT = b < 4096;
    const void* s = isT ? tgt : mem;
    u16* d = isT ? tgt_c : mem_c;
    int i = (((isT ? b : b - 4096) * 256) + threadIdx.x) * 4;
    #pragma unroll
    for (int j = 0; j < 4; ++j) {
        float v; u16 hv;
        if (f) { v = ((const float*)s)[i + j]; hv = f2bf(v); }
        else   { hv = ((const u16*)s)[i + j]; v = bf2f(hv); }
        d[i + j] = hv;
        if (isT) X[i + j] = v;
    }
}

struct VecTab { const void* src[16]; int n[16]; int off[16]; };
__global__ __launch_bounds__(256)
void convert_vecs(VecTab tab, u16* __restrict__ dst, const int* __restrict__ flag) {
    int f = *flag;
    int b = blockIdx.x;
    const void* s = tab.src[b];
    int n = tab.n[b];
    u16* d = dst + tab.off[b];
    for (int i = threadIdx.x; i < n; i += 256)
        d[i] = f ? f2bf(((const float*)s)[i]) : ((const u16*)s)[i];
}

__global__ __launch_bounds__(256)
void store_out(const float* __restrict__ X, void* __restrict__ out, int n,
               const int* __restrict__ flag) {
    int f = *flag;
    int i = (blockIdx.x * 256 + threadIdx.x) * 4;
    if (i < n) {
        #pragma unroll
        for (int j = 0; j < 4; ++j) {
            float v = X[i + j];
            if (f) ((float*)out)[i + j] = v;
            else   ((u16*)out)[i + j] = f2bf(v);
        }
    }
}

// ---------- batched transpose: 10 segments, src[R,C] -> dst[C,R] ----------
struct TransTab {
    const void* src[10]; u16* dst[10];
    int C[10]; int start[10];
};
__global__ __launch_bounds__(256)
void transpose_batch(TransTab tb, const int* __restrict__ flag) {
    int f = *flag;
    int bid = blockIdx.x;
    int seg = 0;
    #pragma unroll
    for (int i = 1; i < 10; ++i) if (bid >= tb.start[i]) seg = i;
    int local = bid - tb.start[seg];
    const void* src = tb.src[seg];
    u16* dst = tb.dst[seg];
    int C = tb.C[seg];
    int ct = C >> 5;
    int by = local / ct, bx = local - by * ct;
    int R = (seg < 8) ? 1024 : ((seg == 8) ? 1024 : 4096);
    __shared__ u16 tile[32][33];
    int tx = threadIdx.x & 31, ty = threadIdx.x >> 5;
    int r0 = by * 32, c0 = bx * 32;
    #pragma unroll
    for (int i = 0; i < 32; i += 8) {
        size_t idx = (size_t)(r0 + ty + i) * C + c0 + tx;
        tile[ty + i][tx] = f ? f2bf(((const float*)src)[idx]) : ((const u16*)src)[idx];
    }
    __syncthreads();
    #pragma unroll
    for (int i = 0; i < 32; i += 8)
        dst[(size_t)(c0 + ty + i) * R + r0 + tx] = tile[tx][ty + i];
}

// ---------- layernorm (row = 1024) ----------
template <typename TIN>
__global__ __launch_bounds__(256)
void lnorm(const TIN* __restrict__ Xin, const u16* __restrict__ gg,
           const u16* __restrict__ bb, u16* __restrict__ Y) {
    const int row = blockIdx.x, t = threadIdx.x;
    const TIN* xr = Xin + (size_t)row * 1024;
    float x[4]; float s1 = 0.f, s2 = 0.f;
    #pragma unroll
    for (int i = 0; i < 4; ++i) {
        float v = load_f(xr[i * 256 + t]);
        x[i] = v; s1 += v; s2 += v * v;
    }
    #pragma unroll
    for (int m = 1; m < 64; m <<= 1) { s1 += __shfl_xor(s1, m, 64); s2 += __shfl_xor(s2, m, 64); }
    __shared__ float red[8];
    if ((t & 63) == 0) { red[(t >> 6) * 2] = s1; red[(t >> 6) * 2 + 1] = s2; }
    __syncthreads();
    s1 = red[0] + red[2] + red[4] + red[6];
    s2 = red[1] + red[3] + red[5] + red[7];
    float mu = s1 * (1.f / 1024.f);
    float var = s2 * (1.f / 1024.f) - mu * mu;
    float rs = rsqrtf(var + 1e-5f);
    #pragma unroll
    for (int i = 0; i < 4; ++i) {
        int idx = i * 256 + t;
        float yv = (x[i] - mu) * rs * bf2f(gg[idx]) + bf2f(bb[idx]);
        Y[(size_t)row * 1024 + idx] = f2bf(yv);
    }
}

// ---------- GEMM (BK=64, XOR-swizzled LDS, XCD-grouped m): ----------
// C[M,N](ldc) = A[M,K] @ Bt[N,K]^T + bias
// epi: 0 = bf16 store, 1 = gelu->bf16, 2 = Xres[idx] += v, 3 = atomicAdd (split-K)
// Block remap: with round-robin block->XCD dispatch, lin&7 selects the XCD;
// grouping bm = (lin&7) + 8*((lin>>3)/gx) pins each XCD to one A m-tile while
// n streams -> A stays resident in that XCD's L2 (A-slice/XCD = A/8).
template <int TM>
__global__ __launch_bounds__(256, 4)
void gemm_bt3(const u16* __restrict__ A, const u16* __restrict__ Bt,
              const u16* __restrict__ bias, u16* __restrict__ C,
              float* __restrict__ Xres, int M, int N, int K, int ldc, int epi) {
    __shared__ alignas(16) u16 As[TM * 64];
    __shared__ alignas(16) u16 Bs[128 * 64];
    constexpr int MI = TM / 32;
    const int t = threadIdx.x;
    const int lane = t & 63, w = t >> 6;
    const int l15 = lane & 15, quad = lane >> 4;
    // XCD-aware remap (gy assumed multiple of 8)
    const int gx = gridDim.x;
    const int lin = blockIdx.y * gx + blockIdx.x;
    const int xcd = lin & 7;
    const int j = lin >> 3;
    const int bn = j % gx;
    const int bm = xcd + 8 * (j / gx);
    const int m0 = bm * TM, n0 = bn * 128;
    const int wm = (w >> 1) * (TM / 2), wn = (w & 1) * 64;
    const int ksl = K / gridDim.z;
    const int kb = blockIdx.z * ksl, ke = kb + ksl;
    const int srow = lane >> 3;                  // 0..7
    const int scol = ((lane & 7) ^ srow) * 8;    // swizzled source chunk
    const u16* ga = A + (size_t)(m0 + w * (TM / 4) + srow) * K + scol;
    const u16* gb = Bt + (size_t)(n0 + w * 32 + srow) * K + scol;
    u16* lA = &As[w * (TM / 4) * 64];
    u16* lB = &Bs[w * 32 * 64];
    floatx4 acc[MI][4] = {};
    const int rsw = l15 & 7;

    for (int k0 = kb; k0 < ke; k0 += 64) {
        __syncthreads();
        #pragma unroll
        for (int c = 0; c < TM / 32; ++c)
            async16(ga + (size_t)(c * 8) * K + k0, lA + c * 8 * 64);
        #pragma unroll
        for (int c = 0; c < 4; ++c)
            async16(gb + (size_t)(c * 8) * K + k0, lB + c * 8 * 64);
        __syncthreads();
        #pragma unroll
        for (int kh = 0; kh < 2; ++kh) {
            const int cofs = ((kh * 4 + quad) ^ rsw) * 8;
            bf16x8 af[MI], bfr[4];
            #pragma unroll
            for (int i = 0; i < MI; ++i)
                af[i] = *(const bf16x8*)&As[(wm + i * 16 + l15) * 64 + cofs];
            #pragma unroll
            for (int i = 0; i < 4; ++i)
                bfr[i] = *(const bf16x8*)&Bs[(wn + i * 16 + l15) * 64 + cofs];
            #pragma unroll
            for (int mi = 0; mi < MI; ++mi)
                #pragma unroll
                for (int ni = 0; ni < 4; ++ni)
                    acc[mi][ni] = mfma_bf16(af[mi], bfr[ni], acc[mi][ni]);
        }
    }

    const bool addb = (blockIdx.z == 0);
    #pragma unroll
    for (int mi = 0; mi < MI; ++mi) {
        #pragma unroll
        for (int ni = 0; ni < 4; ++ni) {
            int gn = n0 + wn + ni * 16 + l15;
            float bv = addb ? bf2f(bias[gn]) : 0.f;
            #pragma unroll
            for (int r = 0; r < 4; ++r) {
                int gm = m0 + wm + mi * 16 + quad * 4 + r;
                float v = acc[mi][ni][r] + bv;
                size_t idx = (size_t)gm * ldc + gn;
                if (epi == 0)      C[idx] = f2bf(v);
                else if (epi == 1) C[idx] = f2bf(gelu_tanh(v));
                else if (epi == 2) Xres[idx] += v;
                else               atomicAdd(&Xres[idx], v);
            }
        }
    }
}

// ---------- flash attention v4: q-tile 64, ones-column MFMA row-sum ----------
// QKV: [B*1024, 3072] bf16 (Q 0.., K 1024.., V 2048..), head h at +h*64.
#define SCL2 0.18033688011112042f  /* 0.125 * log2(e) */
__global__ __launch_bounds__(256, 4)
void attn_fwd4(const u16* __restrict__ QKV, u16* __restrict__ CTX, int causal) {
    __shared__ alignas(16) u16 Ks[64 * 72];   // [key][d]
    __shared__ alignas(16) u16 Vst[64 * 72];  // [d][key^swz]
    __shared__ alignas(16) u16 Sw[4][16 * 72];
    const int t = threadIdx.x;
    const int lane = t & 63, w = t >> 6;
    const int l15 = lane & 15, quad = lane >> 4;
    const int q0 = blockIdx.x * 64, h = blockIdx.y, b = blockIdx.z;
    const int qrow = q0 + w * 16 + l15;
    const u16* qp = QKV + (size_t)(b * 1024 + qrow) * 3072 + h * 64;
    bf16x8 aq0 = *(const bf16x8*)(qp + quad * 8);
    bf16x8 aq1 = *(const bf16x8*)(qp + 32 + quad * 8);
    floatx4 O[4] = {};
    floatx4 Os = {};             // row-sum accumulator (P @ ones)
    float mo[4];
    #pragma unroll
    for (int r = 0; r < 4; ++r) mo[r] = -1e30f;
    bf16x8 ones;
    #pragma unroll
    for (int j = 0; j < 8; ++j) ones[j] = (__bf16)1.0f;

    const int skey = t >> 2, snn = t & 3, sd0 = (t & 3) * 16;
    const int swz = skey ^ (snn << 3);
    const int kend = causal ? (q0 + 64) : 1024;
    for (int kt = 0; kt < kend; kt += 64) {
        __syncthreads();
        {
            const u16* kvb = QKV + (size_t)(b * 1024 + kt + skey) * 3072 + h * 64 + sd0;
            bf16x8 k0v = *(const bf16x8*)(kvb + 1024);
            bf16x8 k1v = *(const bf16x8*)(kvb + 1024 + 8);
            *(bf16x8*)&Ks[skey * 72 + sd0] = k0v;
            *(bf16x8*)&Ks[skey * 72 + sd0 + 8] = k1v;
            bf16x8 v0v = *(const bf16x8*)(kvb + 2048);
            bf16x8 v1v = *(const bf16x8*)(kvb + 2048 + 8);
            #pragma unroll
            for (int j = 0; j < 8; ++j) Vst[(sd0 + j) * 72 + swz] = ((u16*)&v0v)[j];
            #pragma unroll
            for (int j = 0; j < 8; ++j) Vst[(sd0 + 8 + j) * 72 + swz] = ((u16*)&v1v)[j];
        }
        __syncthreads();
        floatx4 S[4];
        #pragma unroll
        for (int kg = 0; kg < 4; ++kg) {
            bf16x8 bk0 = *(const bf16x8*)&Ks[(kg * 16 + l15) * 72 + quad * 8];
            bf16x8 bk1 = *(const bf16x8*)&Ks[(kg * 16 + l15) * 72 + 32 + quad * 8];
            floatx4 z = {};
            z = mfma_bf16(aq0, bk0, z);
            z = mfma_bf16(aq1, bk1, z);
            S[kg] = z;
        }
        const bool domask = causal && (kt == q0);
        float al[4];
        #pragma unroll
        for (int r = 0; r < 4; ++r) {
            #pragma unroll
            for (int kg = 0; kg < 4; ++kg) {
                float s = S[kg][r] * SCL2;   // log2-domain
                if (domask) {
                    int kg_glob = kt + kg * 16 + l15;
                    int qg = q0 + w * 16 + quad * 4 + r;
                    if (kg_glob > qg) s = -1e30f;
                }
                S[kg][r] = s;
            }
            float v = fmaxf(fmaxf(S[0][r], S[1][r]), fmaxf(S[2][r], S[3][r]));
            #pragma unroll
            for (int msk = 1; msk < 16; msk <<= 1) v = fmaxf(v, __shfl_xor(v, msk, 64));
            float mn = fmaxf(mo[r], v);
            al[r] = exp2f(mo[r] - mn);
            #pragma unroll
            for (int kg = 0; kg < 4; ++kg)
                S[kg][r] = exp2f(S[kg][r] - mn);
            mo[r] = mn;
        }
        #pragma unroll
        for (int kg = 0; kg < 4; ++kg)
            #pragma unroll
            for (int r = 0; r < 4; ++r)
                Sw[w][(quad * 4 + r) * 72 + kg * 16 + l15] = f2bf(S[kg][r]);
        #pragma unroll
        for (int g = 0; g < 4; ++g)
            #pragma unroll
            for (int r = 0; r < 4; ++r)
                O[g][r] *= al[r];
        #pragma unroll
        for (int r = 0; r < 4; ++r) Os[r] *= al[r];
        bf16x8 ap0 = *(const bf16x8*)&Sw[w][l15 * 72 + quad * 8];
        bf16x8 ap1 = *(const bf16x8*)&Sw[w][l15 * 72 + 32 + quad * 8];
        #pragma unroll
        for (int g = 0; g < 4; ++g) {
            bf16x8 bv0 = *(const bf16x8*)&Vst[(g * 16 + l15) * 72 + ((quad ^ g) << 3)];
            bf16x8 bv1 = *(const bf16x8*)&Vst[(g * 16 + l15) * 72 + 32 + ((quad ^ g) << 3)];
            O[g] = mfma_bf16(ap0, bv0, O[g]);
            O[g] = mfma_bf16(ap1, bv1, O[g]);
        }
        Os = mfma_bf16(ap0, ones, Os);
        Os = mfma_bf16(ap1, ones, Os);
    }
    #pragma unroll
    for (int r = 0; r < 4; ++r) {
        float inv = 1.0f / Os[r];
        int qg = q0 + w * 16 + quad * 4 + r;
        #pragma unroll
        for (int g = 0; g < 4; ++g)
            CTX[(size_t)(b * 1024 + qg) * 1024 + h * 64 + g * 16 + l15] = f2bf(O[g][r] * inv);
    }
}

// ---------- launch ----------
extern "C" void kernel_launch(void* const* d_in, const int* in_sizes, int n_in,
                              void* d_out, int out_size, void* d_ws, size_t ws_size,
                              hipStream_t stream) {
    const void* tgt_raw    = d_in[0];
    const void* memory_raw = d_in[1];

    char* ws = (char*)d_ws;
    const size_t MiB = 1024 * 1024;
    float* X   = (float*)ws;                  // 0..16 MiB fp32 residual
    u16* Y     = (u16*)(ws + 16 * MiB);       // 16..24
    u16* QKV   = (u16*)(ws + 24 * MiB);       // 24..48  [4096,3072]
    u16* CTX   = (u16*)(ws + 48 * MiB);       // 48..56
    u16* H1    = (u16*)(ws + 24 * MiB);       // 24..56 (overlaps QKV/CTX, dead by FFN)
    u16* wt    = (u16*)(ws + 56 * MiB);       // 56..88 transposed weights
    u16* wqkv_s = wt;                         // [3072,1024]
    u16* wo_s  = wt + 3 * 1048576;
    u16* wq_c  = wt + 4 * 1048576;
    u16* wkv_c = wt + 5 * 1048576;            // [2048,1024]
    u16* wo_c  = wt + 7 * 1048576;
    u16* w1t   = wt + 8 * 1048576;            // [4096,1024]
    u16* w2t   = wt + 12 * 1048576;           // [1024,4096]
    u16* tgt_c = (u16*)(ws + 88 * MiB);
    u16* mem_c = (u16*)(ws + 96 * MiB);
    u16* vecs  = (u16*)(ws + 104 * MiB);
    int* flag  = (int*)(ws + 105 * MiB);

    dim3 blk(256);
    detect_dtype<<<1, blk, 0, stream>>>((const u16*)tgt_raw, flag);
    convert_big<<<8192, blk, 0, stream>>>(tgt_raw, memory_raw, tgt_c, mem_c, X, flag);

    VecTab tab;
    const int srcIdx[16] = {5, 7, 9, 11, 13, 15, 17, 19, 20, 21, 22, 23, 24, 25, 27, 29};
    const int offs[16]   = {0, 1024, 2048, 3072, 4096, 5120, 6144, 7168,
                            8192, 9216, 10240, 11264, 12288, 13312, 14336, 18432};
    for (int i = 0; i < 16; ++i) {
        tab.src[i] = d_in[srcIdx[i]];
        tab.n[i] = (i == 14) ? 4096 : 1024;
        tab.off[i] = offs[i];
    }
    convert_vecs<<<16, blk, 0, stream>>>(tab, vecs, flag);
    u16* b_qkv_s = vecs;            u16* b_o_s  = vecs + 3072;
    u16* b_q_c   = vecs + 4096;     u16* b_kv_c = vecs + 5120;
    u16* b_o_c   = vecs + 7168;
    u16* g1 = vecs + 8192;  u16* be1 = vecs + 9216;
    u16* g2 = vecs + 10240; u16* be2 = vecs + 11264;
    u16* g3 = vecs + 12288; u16* be3 = vecs + 13312;
    u16* b_ff1 = vecs + 14336; u16* b_ff2 = vecs + 18432;

    TransTab tt;
    const void* tsrc[10] = {d_in[4], d_in[6], d_in[8], d_in[10], d_in[12],
                            d_in[14], d_in[16], d_in[18], d_in[26], d_in[28]};
    u16* tdst[10] = {wqkv_s, wqkv_s + 1048576, wqkv_s + 2 * 1048576, wo_s, wq_c,
                     wkv_c, wkv_c + 1048576, wo_c, w1t, w2t};
    int start = 0;
    for (int i = 0; i < 10; ++i) {
        tt.src[i] = tsrc[i]; tt.dst[i] = tdst[i];
        tt.C[i] = (i == 8) ? 4096 : 1024;
        tt.start[i] = start;
        int R = (i == 9) ? 4096 : 1024;
        start += (R / 32) * (tt.C[i] / 32);
    }
    transpose_batch<<<start, blk, 0, stream>>>(tt, flag);

    const int NTOK = 4096;
    dim3 gQKV(24, 32);         // TM=128
    dim3 gKV(16, 64);          // TM=64
    dim3 gFF1(32, 32);         // TM=128
    dim3 gN1k(8, 64);          // TM=64
    dim3 gFF2(8, 64, 2);       // TM=64 + split-K x2
    dim3 ga(16, 16, 4);

    // sublayer 1: self attention (fused QKV projection)
    lnorm<u16><<<4096, blk, 0, stream>>>(tgt_c, g1, be1, Y);
    gemm_bt3<128><<<gQKV, blk, 0, stream>>>(Y, wqkv_s, b_qkv_s, QKV, nullptr, NTOK, 3072, 1024, 3072, 0);
    attn_fwd4<<<ga, blk, 0, stream>>>(QKV, CTX, 1);
    gemm_bt3<64><<<gN1k, blk, 0, stream>>>(CTX, wo_s, b_o_s, nullptr, X, NTOK, 1024, 1024, 1024, 2);

    // sublayer 2: cross attention (fused KV projection from memory)
    lnorm<float><<<4096, blk, 0, stream>>>(X, g2, be2, Y);
    gemm_bt3<64><<<gN1k, blk, 0, stream>>>(Y, wq_c, b_q_c, QKV, nullptr, NTOK, 1024, 1024, 3072, 0);
    gemm_bt3<64><<<gKV, blk, 0, stream>>>(mem_c, wkv_c, b_kv_c, QKV + 1024, nullptr, NTOK, 2048, 1024, 3072, 0);
    attn_fwd4<<<ga, blk, 0, stream>>>(QKV, CTX, 0);
    gemm_bt3<64><<<gN1k, blk, 0, stream>>>(CTX, wo_c, b_o_c, nullptr, X, NTOK, 1024, 1024, 1024, 2);

    // sublayer 3: FFN
    lnorm<float><<<4096, blk, 0, stream>>>(X, g3, be3, Y);
    gemm_bt3<128><<<gFF1, blk, 0, stream>>>(Y, w1t, b_ff1, H1, nullptr, NTOK, 4096, 1024, 4096, 1);
    gemm_bt3<64><<<gFF2, blk, 0, stream>>>(H1, w2t, b_ff2, nullptr, X, NTOK, 1024, 4096, 1024, 3);

    store_out<<<4096, blk, 0, stream>>>(X, d_out, NTOK * 1024, flag);
}